// Round 1
// baseline (158.454 us; speedup 1.0000x reference)
//
#include <hip/hip_runtime.h>

#define DIM 16
#define K_TOK 64   // tokens per 16-lane stream

// out[b*DIM + d] = bias[d]  (d_out is poisoned to 0xAA before every launch)
__global__ void init_out_kernel(float* __restrict__ out,
                                const float* __restrict__ bias,
                                int out_elems) {
    int i = blockIdx.x * blockDim.x + threadIdx.x;
    if (i < out_elems) {
        out[i] = bias[i & (DIM - 1)];
    }
}

// Each group of 16 threads (lane d = tid & 15) processes K_TOK consecutive
// tokens for dim d. segment_ids are sorted, so we run-length accumulate in a
// register and flush to global with atomicAdd only at segment boundaries
// (~TOTAL/50 segments -> ~2.3 flushes per 64-token stream).
__global__ __launch_bounds__(256) void features_linear_kernel(
    const int*   __restrict__ ids,
    const float* __restrict__ ratings,
    const int*   __restrict__ segs,
    const float* __restrict__ weight,
    float*       __restrict__ out,
    int total) {
    int tid = blockIdx.x * blockDim.x + threadIdx.x;
    int d = tid & (DIM - 1);
    int stream_id = tid >> 4;          // 16 lanes per stream
    int t0 = stream_id * K_TOK;
    if (t0 >= total) return;
    int tend = t0 + K_TOK;
    if (tend > total) tend = total;

    float acc = 0.0f;
    int prev_seg = segs[t0];

    for (int t = t0; t < tend; ++t) {
        int seg = segs[t];             // broadcast across the 16-lane group
        if (seg != prev_seg) {
            atomicAdd(&out[prev_seg * DIM + d], acc);
            acc = 0.0f;
            prev_seg = seg;
        }
        int id = ids[t];               // broadcast load
        float r = ratings[t];          // broadcast load
        // 16 lanes read 16 consecutive floats: one coalesced 64B transaction
        acc = fmaf(weight[id * DIM + d], r, acc);
    }
    atomicAdd(&out[prev_seg * DIM + d], acc);
}

extern "C" void kernel_launch(void* const* d_in, const int* in_sizes, int n_in,
                              void* d_out, int out_size, void* d_ws, size_t ws_size,
                              hipStream_t stream) {
    const int*   ids     = (const int*)d_in[0];
    const float* ratings = (const float*)d_in[1];
    const int*   segs    = (const int*)d_in[2];
    // d_in[3] = batch_size scalar (device); batch = out_size / DIM instead
    const float* weight  = (const float*)d_in[4];
    const float* bias    = (const float*)d_in[5];
    float* out = (float*)d_out;

    int total = in_sizes[0];

    // 1) initialize output with bias
    {
        int threads = 256;
        int blocks = (out_size + threads - 1) / threads;
        init_out_kernel<<<blocks, threads, 0, stream>>>(out, bias, out_size);
    }

    // 2) gather + segmented sum
    {
        int n_streams = (total + K_TOK - 1) / K_TOK;   // 16-lane streams
        long long n_threads = (long long)n_streams * DIM;
        int threads = 256;
        int blocks = (int)((n_threads + threads - 1) / threads);
        features_linear_kernel<<<blocks, threads, 0, stream>>>(
            ids, ratings, segs, weight, out, total);
    }
}

// Round 2
// 118.002 us; speedup vs baseline: 1.3428x; 1.3428x over previous
//
#include <hip/hip_runtime.h>

#define DIM 16
#define CHUNK 4
#define NCHUNK 8
#define K_TOK (CHUNK * NCHUNK)   // 32 tokens per 16-lane stream

// out[b*DIM + d] = bias[d], vectorized float4 (d_out poisoned to 0xAA pre-launch)
__global__ void init_out_kernel(float4* __restrict__ out4,
                                const float* __restrict__ bias,
                                int n4) {
    int i = blockIdx.x * blockDim.x + threadIdx.x;
    if (i < n4) {
        int d = (i & 3) * 4;   // DIM=16 -> 4 float4 per row
        out4[i] = make_float4(bias[d], bias[d + 1], bias[d + 2], bias[d + 3]);
    }
}

// 16 lanes per stream (lane d = dim), K_TOK consecutive tokens per stream.
// Unroll-by-4 + software-pipelined index prefetch: 4 independent weight-row
// gathers in flight per wave per iteration (vs 1 in the naive loop).
// Sorted segment_ids -> register run-length accumulate, atomicAdd only at
// segment boundaries.
__global__ __launch_bounds__(256) void features_linear_kernel(
    const int*   __restrict__ ids,
    const float* __restrict__ ratings,
    const int*   __restrict__ segs,
    const float* __restrict__ weight,
    float*       __restrict__ out,
    int total) {
    int tid = blockIdx.x * blockDim.x + threadIdx.x;
    int d = tid & (DIM - 1);
    int stream_id = tid >> 4;
    int t0 = stream_id * K_TOK;
    if (t0 >= total) return;

    float acc = 0.0f;
    int prev = segs[t0];

    if (t0 + K_TOK <= total) {
        // fast path: full chunk-aligned stream (16B-aligned vector loads)
        const int4*   idv = (const int4*)(ids + t0);
        const float4* rv  = (const float4*)(ratings + t0);
        const int4*   sv  = (const int4*)(segs + t0);

        int4   id = idv[0];
        float4 r  = rv[0];
        int4   s  = sv[0];

        #pragma unroll
        for (int c = 0; c < NCHUNK; ++c) {
            // issue 4 independent gathers (compiler groups these before waitcnt)
            float w0 = weight[(size_t)id.x * DIM + d];
            float w1 = weight[(size_t)id.y * DIM + d];
            float w2 = weight[(size_t)id.z * DIM + d];
            float w3 = weight[(size_t)id.w * DIM + d];

            // prefetch next chunk's indices while gathers are in flight
            int4 nid; float4 nr; int4 ns;
            if (c + 1 < NCHUNK) {
                nid = idv[c + 1];
                nr  = rv[c + 1];
                ns  = sv[c + 1];
            }

            if (s.x != prev) { atomicAdd(&out[prev * DIM + d], acc); acc = 0.0f; prev = s.x; }
            acc = fmaf(w0, r.x, acc);
            if (s.y != prev) { atomicAdd(&out[prev * DIM + d], acc); acc = 0.0f; prev = s.y; }
            acc = fmaf(w1, r.y, acc);
            if (s.z != prev) { atomicAdd(&out[prev * DIM + d], acc); acc = 0.0f; prev = s.z; }
            acc = fmaf(w2, r.z, acc);
            if (s.w != prev) { atomicAdd(&out[prev * DIM + d], acc); acc = 0.0f; prev = s.w; }
            acc = fmaf(w3, r.w, acc);

            id = nid; r = nr; s = ns;
        }
    } else {
        // scalar tail (not hit for TOTAL=819200, K_TOK=32, but stay general)
        int tend = total;
        for (int t = t0; t < tend; ++t) {
            int seg = segs[t];
            if (seg != prev) {
                atomicAdd(&out[prev * DIM + d], acc);
                acc = 0.0f;
                prev = seg;
            }
            acc = fmaf(weight[(size_t)ids[t] * DIM + d], ratings[t], acc);
        }
    }
    atomicAdd(&out[prev * DIM + d], acc);
}

extern "C" void kernel_launch(void* const* d_in, const int* in_sizes, int n_in,
                              void* d_out, int out_size, void* d_ws, size_t ws_size,
                              hipStream_t stream) {
    const int*   ids     = (const int*)d_in[0];
    const float* ratings = (const float*)d_in[1];
    const int*   segs    = (const int*)d_in[2];
    // d_in[3] = batch_size scalar (unused; batch = out_size / DIM)
    const float* weight  = (const float*)d_in[4];
    const float* bias    = (const float*)d_in[5];
    float* out = (float*)d_out;

    int total = in_sizes[0];

    // 1) initialize output with bias (vectorized)
    {
        int n4 = out_size / 4;
        int threads = 256;
        int blocks = (n4 + threads - 1) / threads;
        init_out_kernel<<<blocks, threads, 0, stream>>>((float4*)out, bias, n4);
    }

    // 2) gather + segmented sum
    {
        int n_streams = (total + K_TOK - 1) / K_TOK;
        long long n_threads = (long long)n_streams * DIM;
        int threads = 256;
        int blocks = (int)((n_threads + threads - 1) / threads);
        features_linear_kernel<<<blocks, threads, 0, stream>>>(
            ids, ratings, segs, weight, out, total);
    }
}

// Round 3
// 116.444 us; speedup vs baseline: 1.3608x; 1.0134x over previous
//
#include <hip/hip_runtime.h>

#define DIM 16
#define K_TOK 16   // tokens per 16-lane stream; fully unrolled, 16 gathers in flight

// out[b*DIM + d] = bias[d], vectorized float4 (d_out poisoned to 0xAA pre-launch)
__global__ void init_out_kernel(float4* __restrict__ out4,
                                const float* __restrict__ bias,
                                int n4) {
    int i = blockIdx.x * blockDim.x + threadIdx.x;
    if (i < n4) {
        int d = (i & 3) * 4;   // DIM=16 -> 4 float4 per row
        out4[i] = make_float4(bias[d], bias[d + 1], bias[d + 2], bias[d + 3]);
    }
}

// 16 lanes per stream (lane = dim), 16 consecutive tokens per stream.
// All index/rating/seg data loaded as dwordx4, then ALL 16 weight-row gathers
// issued before any use -> up to 64 outstanding 64B requests per wave
// (4 groups x 16 gathers). Sorted segment_ids -> register run-length
// accumulate; atomicAdd only at segment boundaries.
__global__ __launch_bounds__(256) void features_linear_kernel(
    const int*   __restrict__ ids,
    const float* __restrict__ ratings,
    const int*   __restrict__ segs,
    const float* __restrict__ weight,
    float*       __restrict__ out,
    int total) {
    int tid = blockIdx.x * blockDim.x + threadIdx.x;
    int d = tid & (DIM - 1);
    int stream_id = tid >> 4;
    int t0 = stream_id * K_TOK;
    if (t0 >= total) return;

    float acc = 0.0f;
    int prev = segs[t0];

    if (t0 + K_TOK <= total) {
        const int4*   idv = (const int4*)(ids + t0);
        const float4* rv  = (const float4*)(ratings + t0);
        const int4*   sv  = (const int4*)(segs + t0);

        int4   id0 = idv[0], id1 = idv[1], id2 = idv[2], id3 = idv[3];
        float4 r0  = rv[0],  r1  = rv[1],  r2  = rv[2],  r3  = rv[3];
        int4   s0  = sv[0],  s1  = sv[1],  s2  = sv[2],  s3  = sv[3];

        // issue 16 independent gathers before consuming any
        float w0  = weight[(size_t)id0.x * DIM + d];
        float w1  = weight[(size_t)id0.y * DIM + d];
        float w2  = weight[(size_t)id0.z * DIM + d];
        float w3  = weight[(size_t)id0.w * DIM + d];
        float w4  = weight[(size_t)id1.x * DIM + d];
        float w5  = weight[(size_t)id1.y * DIM + d];
        float w6  = weight[(size_t)id1.z * DIM + d];
        float w7  = weight[(size_t)id1.w * DIM + d];
        float w8  = weight[(size_t)id2.x * DIM + d];
        float w9  = weight[(size_t)id2.y * DIM + d];
        float w10 = weight[(size_t)id2.z * DIM + d];
        float w11 = weight[(size_t)id2.w * DIM + d];
        float w12 = weight[(size_t)id3.x * DIM + d];
        float w13 = weight[(size_t)id3.y * DIM + d];
        float w14 = weight[(size_t)id3.z * DIM + d];
        float w15 = weight[(size_t)id3.w * DIM + d];

        #define STEP(sv_, wv_, rv_)                                        \
            if ((sv_) != prev) {                                           \
                atomicAdd(&out[prev * DIM + d], acc);                      \
                acc = 0.0f; prev = (sv_);                                  \
            }                                                              \
            acc = fmaf((wv_), (rv_), acc);

        STEP(s0.x, w0,  r0.x)  STEP(s0.y, w1,  r0.y)
        STEP(s0.z, w2,  r0.z)  STEP(s0.w, w3,  r0.w)
        STEP(s1.x, w4,  r1.x)  STEP(s1.y, w5,  r1.y)
        STEP(s1.z, w6,  r1.z)  STEP(s1.w, w7,  r1.w)
        STEP(s2.x, w8,  r2.x)  STEP(s2.y, w9,  r2.y)
        STEP(s2.z, w10, r2.z)  STEP(s2.w, w11, r2.w)
        STEP(s3.x, w12, r3.x)  STEP(s3.y, w13, r3.y)
        STEP(s3.z, w14, r3.z)  STEP(s3.w, w15, r3.w)
        #undef STEP
    } else {
        // scalar tail (not hit for TOTAL=819200, but stay general)
        for (int t = t0; t < total; ++t) {
            int seg = segs[t];
            if (seg != prev) {
                atomicAdd(&out[prev * DIM + d], acc);
                acc = 0.0f;
                prev = seg;
            }
            acc = fmaf(weight[(size_t)ids[t] * DIM + d], ratings[t], acc);
        }
    }
    atomicAdd(&out[prev * DIM + d], acc);
}

extern "C" void kernel_launch(void* const* d_in, const int* in_sizes, int n_in,
                              void* d_out, int out_size, void* d_ws, size_t ws_size,
                              hipStream_t stream) {
    const int*   ids     = (const int*)d_in[0];
    const float* ratings = (const float*)d_in[1];
    const int*   segs    = (const int*)d_in[2];
    // d_in[3] = batch_size scalar (unused; batch = out_size / DIM)
    const float* weight  = (const float*)d_in[4];
    const float* bias    = (const float*)d_in[5];
    float* out = (float*)d_out;

    int total = in_sizes[0];

    // 1) initialize output with bias (vectorized)
    {
        int n4 = out_size / 4;
        int threads = 256;
        int blocks = (n4 + threads - 1) / threads;
        init_out_kernel<<<blocks, threads, 0, stream>>>((float4*)out, bias, n4);
    }

    // 2) gather + segmented sum
    {
        int n_streams = (total + K_TOK - 1) / K_TOK;
        long long n_threads = (long long)n_streams * DIM;
        int threads = 256;
        int blocks = (int)((n_threads + threads - 1) / threads);
        features_linear_kernel<<<blocks, threads, 0, stream>>>(
            ids, ratings, segs, weight, out, total);
    }
}